// Round 1
// baseline (195.547 us; speedup 1.0000x reference)
//
#include <hip/hip_runtime.h>

typedef _Float16 half2_t __attribute__((ext_vector_type(2)));

#if defined(__has_builtin)
#if __has_builtin(__builtin_amdgcn_fdot2)
#define HAS_FDOT2 1
#endif
#endif

static __device__ __forceinline__ float fdot2(half2_t a, half2_t b, float c) {
#ifdef HAS_FDOT2
    return __builtin_amdgcn_fdot2(a, b, c, false);
#else
    return (float)a.x * (float)b.x + (float)a.y * (float)b.y + c;
#endif
}

#define OUT_Q 1ull
#define OUT_P 8388609ull
#define OUT_E 8388610ull

// ws layout: bytes [0,2048): uint hist[512]; floats ws[512..2560): per-wave loss partials
__global__ __launch_bounds__(256, 2)
void vq_main(const float* __restrict__ in, const float* __restrict__ emb,
             float* __restrict__ out, float* __restrict__ ws) {
    __shared__ unsigned int e2_lds[8192];   // 256 codes x 32 half2 (32 KB)
    __shared__ float ebias_lds[256];
    __shared__ unsigned int hist_lds[512];

    const int tid  = threadIdx.x;
    const int lane = tid & 63;
    const int wid  = tid >> 6;
    const int pb   = blockIdx.x * 256 + wid * 64;   // wave pixel base
    const int b    = pb >> 10;
    const int hw0  = pb & 1023;

    hist_lds[tid] = 0u; hist_lds[tid + 256] = 0u;

    // ---- load this lane's pixel vector (64 ch, NCHW strided -> coalesced across lanes)
    const float* xp = in + (size_t)b * 65536 + hw0 + lane;
    half2_t xh[32];
    float sumsq = 0.0f;
#pragma unroll
    for (int j = 0; j < 32; ++j) {
        float v0 = xp[(size_t)(2 * j) * 1024];
        float v1 = xp[(size_t)(2 * j + 1) * 1024];
        sumsq += v0 * v0;
        sumsq += v1 * v1;
        half2_t h; h.x = (_Float16)v0; h.y = (_Float16)v1;
        xh[j] = h;
    }

    float minv = __builtin_inff();
    int   mink = 0;

    for (int half = 0; half < 2; ++half) {
        __syncthreads();   // protect LDS buffer reuse
        // stage 256 codes as f16 pairs (coalesced float2 loads)
        const float2* ef = reinterpret_cast<const float2*>(emb) + half * 8192;
        for (int i = tid; i < 8192; i += 256) {
            float2 v = ef[i];
            half2_t h; h.x = (_Float16)v.x; h.y = (_Float16)v.y;
            e2_lds[i] = __builtin_bit_cast(unsigned int, h);
        }
        __syncthreads();
        // per-code |e|^2 from the f16 values; rotated reads avoid bank conflicts
        {
            float s = 0.0f;
            for (int j = 0; j < 32; ++j) {
                unsigned int u = e2_lds[(tid << 5) + ((j + tid) & 31)];
                half2_t h = __builtin_bit_cast(half2_t, u);
                float a = (float)h.x, c = (float)h.y;
                s += a * a + c * c;
            }
            ebias_lds[tid] = s;
        }
        __syncthreads();
        // argmin over these 256 codes: score = |e|^2 - 2 x.e
        for (int kk = 0; kk < 256; ++kk) {
            const uint4* erow = reinterpret_cast<const uint4*>(e2_lds + (kk << 5));
            float a0 = 0.f, a1 = 0.f, a2 = 0.f, a3 = 0.f;
#pragma unroll
            for (int jj = 0; jj < 8; ++jj) {
                uint4 q = erow[jj];
                a0 = fdot2(xh[4 * jj + 0], __builtin_bit_cast(half2_t, q.x), a0);
                a1 = fdot2(xh[4 * jj + 1], __builtin_bit_cast(half2_t, q.y), a1);
                a2 = fdot2(xh[4 * jj + 2], __builtin_bit_cast(half2_t, q.z), a2);
                a3 = fdot2(xh[4 * jj + 3], __builtin_bit_cast(half2_t, q.w), a3);
            }
            float dot = (a0 + a1) + (a2 + a3);
            float s = __builtin_fmaf(-2.0f, dot, ebias_lds[kk]);
            if (s < minv) { minv = s; mink = (half << 8) + kk; }
        }
    }

    // ---- histogram (LDS int atomics)
    __syncthreads();
    atomicAdd(&hist_lds[mink], 1u);

    // ---- per-wave loss partial (deterministic: fixed reduction + fixed slot)
    float lossp = minv + sumsq;   // = min squared distance incl |x|^2
#pragma unroll
    for (int off = 32; off > 0; off >>= 1)
        lossp += __shfl_down(lossp, off, 64);
    if (lane == 0) ws[512 + blockIdx.x * 4 + wid] = lossp;

    // ---- one-hot rows, row-cooperative coalesced writes (8B aligned)
    {
        float* encw = out + OUT_E + (size_t)pb * 512;
        const int e0 = lane * 8;
        for (int r = 0; r < 64; ++r) {
            int idx_r = __shfl(mink, r, 64);
            uint2* rowp = reinterpret_cast<uint2*>(encw + (size_t)r * 512 + e0);
#pragma unroll
            for (int j = 0; j < 4; ++j) {
                uint2 v;
                v.x = (e0 + 2 * j     == idx_r) ? 0x3f800000u : 0u;
                v.y = (e0 + 2 * j + 1 == idx_r) ? 0x3f800000u : 0u;
                rowp[j] = v;
            }
        }
    }

    // ---- quantized NCHW: per-lane gather of e-row (L2-resident), coalesced stores
    {
        const float* eq = emb + mink * 64;
        float* q = out + OUT_Q + (size_t)b * 65536 + hw0 + lane;
#pragma unroll 8
        for (int c = 0; c < 64; ++c)
            q[(size_t)c * 1024] = eq[c];
    }

    // ---- merge histogram into ws
    __syncthreads();
    {
        unsigned int* gh = reinterpret_cast<unsigned int*>(ws);
        atomicAdd(&gh[tid], hist_lds[tid]);
        atomicAdd(&gh[tid + 256], hist_lds[tid + 256]);
    }
}

__global__ void vq_finalize(const float* __restrict__ ws, float* __restrict__ out) {
    __shared__ float rl[512], re[512];
    const int t = threadIdx.x;
    const unsigned int* hist = reinterpret_cast<const unsigned int*>(ws);
    const float* lp = ws + 512;
    float l = lp[t] + lp[t + 512] + lp[t + 1024] + lp[t + 1536];
    float p = (float)hist[t] * (1.0f / 131072.0f);
    rl[t] = l;
    re[t] = p * logf(p + 1e-10f);
    for (int off = 256; off > 0; off >>= 1) {
        __syncthreads();
        if (t < off) { rl[t] += rl[t + off]; re[t] += re[t + off]; }
    }
    if (t == 0) {
        out[0]       = 1.25f * rl[0] / 8388608.0f;   // q_latent + 0.25*e_latent
        out[OUT_P]   = expf(-re[0]);                 // perplexity
    }
}

extern "C" void kernel_launch(void* const* d_in, const int* in_sizes, int n_in,
                              void* d_out, int out_size, void* d_ws, size_t ws_size,
                              hipStream_t stream) {
    const float* in  = (const float*)d_in[0];
    const float* emb = (const float*)d_in[1];
    float* out = (float*)d_out;
    float* ws  = (float*)d_ws;

    hipMemsetAsync(d_ws, 0, 2048, stream);           // zero histogram bins
    vq_main<<<dim3(512), dim3(256), 0, stream>>>(in, emb, out, ws);
    vq_finalize<<<dim3(1), dim3(512), 0, stream>>>(ws, out);
}

// Round 2
// 133.143 us; speedup vs baseline: 1.4687x; 1.4687x over previous
//
#include <hip/hip_runtime.h>

typedef _Float16 half8 __attribute__((ext_vector_type(8)));
typedef float f32x4 __attribute__((ext_vector_type(4)));

#define OUT_Q 1ull
#define OUT_P 8388609ull
#define OUT_E 8388610ull

// ws layout (floats): [0,512) uint hist; [512,4608) per-wave loss partials;
// [4608,5120) ebias f32; [5120, 5120+32768) f16 codebook (65536 halves)

__global__ void vq_prep(const float* __restrict__ emb, _Float16* __restrict__ e16,
                        float* __restrict__ ebias) {
    const int l = threadIdx.x;          // 64 threads = 1 wave, lane = channel
    const int base = blockIdx.x * 64;   // 8 blocks x 64 codes
    for (int k = 0; k < 64; ++k) {
        const int code = base + k;
        float v = emb[code * 64 + l];
        _Float16 h = (_Float16)v;
        e16[code * 64 + l] = h;
        float s = (float)h * (float)h;
#pragma unroll
        for (int off = 32; off > 0; off >>= 1) s += __shfl_down(s, off, 64);
        if (l == 0) ebias[code] = s;
    }
}

__global__ __launch_bounds__(256, 4)
void vq_main(const float* __restrict__ in, const float* __restrict__ emb,
             const _Float16* __restrict__ e16, const float* __restrict__ ebias,
             float* __restrict__ out, float* __restrict__ ws) {
    __shared__ int idx_lds[128];
    __shared__ unsigned int hist_lds[512];

    const int tid  = threadIdx.x;
    const int lane = tid & 63;
    const int wid  = tid >> 6;
    const int pb   = blockIdx.x * 128;      // block pixel base (128-aligned)
    const int b    = pb >> 10;
    const int hw0  = pb & 1023;

    hist_lds[tid] = 0u; hist_lds[tid + 256] = 0u;

    const int col = lane & 15;   // MFMA col: pixel for A-load, code for C
    const int g   = lane >> 4;   // k-group

    // ---- A fragments: lane holds pixel (ptile*16+col), k = g*8..+8 per kstep.
    // Pre-scaled by -2 so MFMA directly yields |e|^2 - 2 x.e when acc starts at |e|^2.
    half8 afrag[2][2];
    float sumsq = 0.0f;                       // per-lane partial of |x|^2
    const float* xbase = in + (size_t)b * 65536 + hw0 + wid * 32;
#pragma unroll
    for (int i = 0; i < 2; ++i) {
        const float* xp = xbase + i * 16 + col;
#pragma unroll
        for (int ks = 0; ks < 2; ++ks) {
#pragma unroll
            for (int e = 0; e < 8; ++e) {
                float v = xp[(size_t)(ks * 32 + g * 8 + e) * 1024];
                sumsq += v * v;
                afrag[i][ks][e] = (_Float16)(-2.0f * v);
            }
        }
    }

    // ---- 32 code-tiles of 16: acc init = |e|^2, 2 MFMA per ptile, 3-op min update
    float minv[2][4];
    int   mint[2][4];
#pragma unroll
    for (int i = 0; i < 2; ++i)
#pragma unroll
        for (int r = 0; r < 4; ++r) { minv[i][r] = __builtin_inff(); mint[i][r] = 0; }

#pragma unroll 2
    for (int t = 0; t < 32; ++t) {
        const float bias = ebias[(t << 4) + col];
        half8 bfrag[2];
#pragma unroll
        for (int ks = 0; ks < 2; ++ks)
            bfrag[ks] = *reinterpret_cast<const half8*>(
                e16 + ((size_t)((t << 4) + col) << 6) + ks * 32 + g * 8);
#pragma unroll
        for (int i = 0; i < 2; ++i) {
            f32x4 acc = { bias, bias, bias, bias };
            acc = __builtin_amdgcn_mfma_f32_16x16x32_f16(afrag[i][0], bfrag[0], acc, 0, 0, 0);
            acc = __builtin_amdgcn_mfma_f32_16x16x32_f16(afrag[i][1], bfrag[1], acc, 0, 0, 0);
#pragma unroll
            for (int r = 0; r < 4; ++r) {
                if (acc[r] < minv[i][r]) { minv[i][r] = acc[r]; mint[i][r] = t; }
            }
        }
    }

    // ---- cross-lane argmin over the 16 code-columns (pixel = g*4+r of ptile i)
    float vsum = 0.0f;   // lane-local sum of winning scores (col==0 lanes only)
#pragma unroll
    for (int i = 0; i < 2; ++i) {
#pragma unroll
        for (int r = 0; r < 4; ++r) {
            float v = minv[i][r];
            int   k = (mint[i][r] << 4) + col;
#pragma unroll
            for (int off = 1; off < 16; off <<= 1) {
                float v2 = __shfl_xor(v, off, 64);
                int   k2 = __shfl_xor(k, off, 64);
                if (v2 < v || (v2 == v && k2 < k)) { v = v2; k = k2; }
            }
            if (col == 0) {
                idx_lds[wid * 32 + i * 16 + g * 4 + r] = k;
                vsum += v;
            }
        }
    }

    // ---- per-wave loss partial: sum of (min score) + sum of |x|^2
    float lossp = vsum + sumsq;
#pragma unroll
    for (int off = 32; off > 0; off >>= 1) lossp += __shfl_down(lossp, off, 64);
    if (lane == 0) ws[512 + blockIdx.x * 4 + wid] = lossp;

    __syncthreads();

    // ---- histogram (LDS atomics, one per pixel)
    if (tid < 128) atomicAdd(&hist_lds[idx_lds[tid]], 1u);

    // ---- one-hot: 256 threads x 8B = one 2KB row per instruction
    {
        float* encw = out + OUT_E + (size_t)pb * 512;
        const int e0 = tid * 2;
        for (int r = 0; r < 128; ++r) {
            const int idx = idx_lds[r];
            uint2 v;
            v.x = (e0     == idx) ? 0x3f800000u : 0u;
            v.y = (e0 + 1 == idx) ? 0x3f800000u : 0u;
            *reinterpret_cast<uint2*>(encw + (size_t)r * 512 + e0) = v;
        }
    }

    // ---- quantized NCHW: gather winning f32 e-row, pixel-coalesced stores
    {
        const int p   = tid & 127;
        const int ch0 = (tid >> 7) * 32;
        const float* eq = emb + idx_lds[p] * 64;
        float* q = out + OUT_Q + (size_t)b * 65536 + hw0 + p;
#pragma unroll 8
        for (int c = ch0; c < ch0 + 32; ++c)
            q[(size_t)c * 1024] = eq[c];
    }

    // ---- merge histogram into ws (skip empty bins)
    __syncthreads();
    {
        unsigned int* gh = reinterpret_cast<unsigned int*>(ws);
        unsigned int h0 = hist_lds[tid], h1 = hist_lds[tid + 256];
        if (h0) atomicAdd(&gh[tid], h0);
        if (h1) atomicAdd(&gh[tid + 256], h1);
    }
}

__global__ void vq_finalize(const float* __restrict__ ws, float* __restrict__ out) {
    __shared__ float rl[512], re[512];
    const int t = threadIdx.x;
    const unsigned int* hist = reinterpret_cast<const unsigned int*>(ws);
    const float* lp = ws + 512;
    float l = 0.0f;
#pragma unroll
    for (int j = 0; j < 8; ++j) l += lp[t + 512 * j];
    float p = (float)hist[t] * (1.0f / 131072.0f);
    rl[t] = l;
    re[t] = p * logf(p + 1e-10f);
    for (int off = 256; off > 0; off >>= 1) {
        __syncthreads();
        if (t < off) { rl[t] += rl[t + off]; re[t] += re[t + off]; }
    }
    if (t == 0) {
        out[0]     = 1.25f * rl[0] / 8388608.0f;   // (1 + commitment_cost) * mean dist
        out[OUT_P] = expf(-re[0]);                 // perplexity
    }
}

extern "C" void kernel_launch(void* const* d_in, const int* in_sizes, int n_in,
                              void* d_out, int out_size, void* d_ws, size_t ws_size,
                              hipStream_t stream) {
    (void)in_sizes; (void)n_in; (void)out_size; (void)ws_size;
    const float* in  = (const float*)d_in[0];
    const float* emb = (const float*)d_in[1];
    float* out = (float*)d_out;
    float* ws  = (float*)d_ws;
    _Float16* e16 = (_Float16*)(ws + 5120);
    float* ebias  = ws + 4608;

    hipMemsetAsync(d_ws, 0, 2048, stream);   // zero histogram bins
    vq_prep<<<dim3(8), dim3(64), 0, stream>>>(emb, e16, ebias);
    vq_main<<<dim3(1024), dim3(256), 0, stream>>>(in, emb, e16, ebias, out, ws);
    vq_finalize<<<dim3(1), dim3(512), 0, stream>>>(ws, out);
}

// Round 3
// 110.472 us; speedup vs baseline: 1.7701x; 1.2052x over previous
//
#include <hip/hip_runtime.h>

typedef _Float16 half8 __attribute__((ext_vector_type(8)));
typedef float f32x4 __attribute__((ext_vector_type(4)));

#define OUT_Q 1ull
#define OUT_P 8388609ull
#define OUT_E 8388610ull

// ws layout (floats): [0,512) uint hist; [512,4608) per-wave loss partials;
// [4608,5120) ebias f32; [5120, 5120+16384) f16 codebook (32768 halves)

__global__ __launch_bounds__(64)
void vq_prep(const float* __restrict__ emb, _Float16* __restrict__ e16,
             float* __restrict__ ebias, unsigned int* __restrict__ hist) {
    const int lane = threadIdx.x;       // = channel
    const int base = blockIdx.x * 8;    // 64 blocks x 8 codes
    if (lane < 8) hist[base + lane] = 0u;   // replaces the memset node
    float v[8];
#pragma unroll
    for (int j = 0; j < 8; ++j) v[j] = emb[(base + j) * 64 + lane];
#pragma unroll
    for (int j = 0; j < 8; ++j) {
        _Float16 h = (_Float16)v[j];
        e16[(base + j) * 64 + lane] = h;
        float s = (float)h * (float)h;
#pragma unroll
        for (int off = 32; off > 0; off >>= 1) s += __shfl_down(s, off, 64);
        if (lane == 0) ebias[base + j] = s;
    }
}

__global__ __launch_bounds__(256, 4)
void vq_main(const float* __restrict__ in, const float* __restrict__ emb,
             const _Float16* __restrict__ e16, const float* __restrict__ ebias,
             float* __restrict__ out, float* __restrict__ ws) {
    __shared__ int idx_lds[128];
    __shared__ unsigned int hist_lds[512];

    const int tid  = threadIdx.x;
    const int lane = tid & 63;
    const int wid  = tid >> 6;
    const int pb   = blockIdx.x * 128;      // block pixel base (128-aligned)
    const int b    = pb >> 10;
    const int hw0  = pb & 1023;

    hist_lds[tid] = 0u; hist_lds[tid + 256] = 0u;

    const int col = lane & 15;   // MFMA col: pixel for A-load, code for C
    const int g   = lane >> 4;   // k-group

    // ---- A fragments: lane holds pixel (ptile*16+col), k = g*8..+8 per kstep.
    // Pre-scaled by -2 so MFMA directly yields |e|^2 - 2 x.e when acc starts at |e|^2.
    half8 afrag[2][2];
    float sumsq = 0.0f;                       // per-lane partial of |x|^2
    const float* xbase = in + (size_t)b * 65536 + hw0 + wid * 32;
#pragma unroll
    for (int i = 0; i < 2; ++i) {
        const float* xp = xbase + i * 16 + col;
#pragma unroll
        for (int ks = 0; ks < 2; ++ks) {
#pragma unroll
            for (int e = 0; e < 8; ++e) {
                float v = xp[(size_t)(ks * 32 + g * 8 + e) * 1024];
                sumsq += v * v;
                afrag[i][ks][e] = (_Float16)(-2.0f * v);
            }
        }
    }

    // ---- 32 code-tiles of 16: acc init = |e|^2, 2 MFMA per ptile, 3-op min update
    float minv[2][4];
    int   mint[2][4];
#pragma unroll
    for (int i = 0; i < 2; ++i)
#pragma unroll
        for (int r = 0; r < 4; ++r) { minv[i][r] = __builtin_inff(); mint[i][r] = 0; }

#pragma unroll 2
    for (int t = 0; t < 32; ++t) {
        const float bias = ebias[(t << 4) + col];
        half8 bfrag[2];
#pragma unroll
        for (int ks = 0; ks < 2; ++ks)
            bfrag[ks] = *reinterpret_cast<const half8*>(
                e16 + ((size_t)((t << 4) + col) << 6) + ks * 32 + g * 8);
#pragma unroll
        for (int i = 0; i < 2; ++i) {
            f32x4 acc = { bias, bias, bias, bias };
            acc = __builtin_amdgcn_mfma_f32_16x16x32_f16(afrag[i][0], bfrag[0], acc, 0, 0, 0);
            acc = __builtin_amdgcn_mfma_f32_16x16x32_f16(afrag[i][1], bfrag[1], acc, 0, 0, 0);
#pragma unroll
            for (int r = 0; r < 4; ++r) {
                if (acc[r] < minv[i][r]) { minv[i][r] = acc[r]; mint[i][r] = t; }
            }
        }
    }

    // ---- cross-lane argmin over the 16 code-columns (pixel = g*4+r of ptile i)
    float vsum = 0.0f;   // lane-local sum of winning scores (col==0 lanes only)
#pragma unroll
    for (int i = 0; i < 2; ++i) {
#pragma unroll
        for (int r = 0; r < 4; ++r) {
            float v = minv[i][r];
            int   k = (mint[i][r] << 4) + col;
#pragma unroll
            for (int off = 1; off < 16; off <<= 1) {
                float v2 = __shfl_xor(v, off, 64);
                int   k2 = __shfl_xor(k, off, 64);
                if (v2 < v || (v2 == v && k2 < k)) { v = v2; k = k2; }
            }
            if (col == 0) {
                idx_lds[wid * 32 + i * 16 + g * 4 + r] = k;
                vsum += v;
            }
        }
    }

    // ---- per-wave loss partial: sum of (min score) + sum of |x|^2
    float lossp = vsum + sumsq;
#pragma unroll
    for (int off = 32; off > 0; off >>= 1) lossp += __shfl_down(lossp, off, 64);
    if (lane == 0) ws[512 + blockIdx.x * 4 + wid] = lossp;

    __syncthreads();

    // ---- histogram (LDS atomics, one per pixel)
    if (tid < 128) atomicAdd(&hist_lds[idx_lds[tid]], 1u);

    // ---- one-hot: 256 threads x 8B = one 2KB row per instruction; 2 rows jammed
    {
        float* encw = out + OUT_E + (size_t)pb * 512;
        const int e0 = tid * 2;
        for (int r = 0; r < 128; r += 2) {
            const int idx0 = idx_lds[r];
            const int idx1 = idx_lds[r + 1];
            uint2 v0, v1;
            v0.x = (e0     == idx0) ? 0x3f800000u : 0u;
            v0.y = (e0 + 1 == idx0) ? 0x3f800000u : 0u;
            v1.x = (e0     == idx1) ? 0x3f800000u : 0u;
            v1.y = (e0 + 1 == idx1) ? 0x3f800000u : 0u;
            *reinterpret_cast<uint2*>(encw + (size_t)r * 512 + e0)       = v0;
            *reinterpret_cast<uint2*>(encw + (size_t)(r + 1) * 512 + e0) = v1;
        }
    }

    // ---- quantized NCHW: gather winning f32 e-row, pixel-coalesced stores
    {
        const int p   = tid & 127;
        const int ch0 = (tid >> 7) * 32;
        const float* eq = emb + idx_lds[p] * 64;
        float* q = out + OUT_Q + (size_t)b * 65536 + hw0 + p;
#pragma unroll 8
        for (int c = ch0; c < ch0 + 32; ++c)
            q[(size_t)c * 1024] = eq[c];
    }

    // ---- merge histogram into ws (skip empty bins)
    __syncthreads();
    {
        unsigned int* gh = reinterpret_cast<unsigned int*>(ws);
        unsigned int h0 = hist_lds[tid], h1 = hist_lds[tid + 256];
        if (h0) atomicAdd(&gh[tid], h0);
        if (h1) atomicAdd(&gh[tid + 256], h1);
    }
}

__global__ void vq_finalize(const float* __restrict__ ws, float* __restrict__ out) {
    __shared__ float rl[512], re[512];
    const int t = threadIdx.x;
    const unsigned int* hist = reinterpret_cast<const unsigned int*>(ws);
    const float* lp = ws + 512;
    float l = 0.0f;
#pragma unroll
    for (int j = 0; j < 8; ++j) l += lp[t + 512 * j];
    float p = (float)hist[t] * (1.0f / 131072.0f);
    rl[t] = l;
    re[t] = p * logf(p + 1e-10f);
    for (int off = 256; off > 0; off >>= 1) {
        __syncthreads();
        if (t < off) { rl[t] += rl[t + off]; re[t] += re[t + off]; }
    }
    if (t == 0) {
        out[0]     = 1.25f * rl[0] / 8388608.0f;   // (1 + commitment_cost) * mean dist
        out[OUT_P] = expf(-re[0]);                 // perplexity
    }
}

extern "C" void kernel_launch(void* const* d_in, const int* in_sizes, int n_in,
                              void* d_out, int out_size, void* d_ws, size_t ws_size,
                              hipStream_t stream) {
    (void)in_sizes; (void)n_in; (void)out_size; (void)ws_size;
    const float* in  = (const float*)d_in[0];
    const float* emb = (const float*)d_in[1];
    float* out = (float*)d_out;
    float* ws  = (float*)d_ws;
    _Float16* e16 = (_Float16*)(ws + 5120);
    float* ebias  = ws + 4608;
    unsigned int* hist = (unsigned int*)d_ws;

    vq_prep<<<dim3(64), dim3(64), 0, stream>>>(emb, e16, ebias, hist);
    vq_main<<<dim3(1024), dim3(256), 0, stream>>>(in, emb, e16, ebias, out, ws);
    vq_finalize<<<dim3(1), dim3(512), 0, stream>>>(ws, out);
}

// Round 4
// 99.770 us; speedup vs baseline: 1.9600x; 1.1073x over previous
//
#include <hip/hip_runtime.h>

typedef _Float16 half8 __attribute__((ext_vector_type(8)));
typedef float f32x4 __attribute__((ext_vector_type(4)));

#define OUT_Q 1ull
#define OUT_P 8388609ull
#define OUT_E 8388610ull

// ws layout (floats): [0,512) uint hist; [512,4608) per-wave loss partials;
// [4608,5120) ebias f32; [5120, 5120+16384) f16 codebook (32768 halves)

__global__ __launch_bounds__(64)
void vq_prep(const float* __restrict__ emb, _Float16* __restrict__ e16,
             float* __restrict__ ebias, unsigned int* __restrict__ hist) {
    const int lane = threadIdx.x;       // = channel
    const int base = blockIdx.x * 8;    // 64 blocks x 8 codes
    if (lane < 8) hist[base + lane] = 0u;   // replaces a memset node
    float v[8];
#pragma unroll
    for (int j = 0; j < 8; ++j) v[j] = emb[(base + j) * 64 + lane];
#pragma unroll
    for (int j = 0; j < 8; ++j) {
        _Float16 h = (_Float16)v[j];
        e16[(base + j) * 64 + lane] = h;
        float s = (float)h * (float)h;
#pragma unroll
        for (int off = 32; off > 0; off >>= 1) s += __shfl_down(s, off, 64);
        if (lane == 0) ebias[base + j] = s;
    }
}

__global__ __launch_bounds__(256, 4)
void vq_main(const float* __restrict__ in, const float* __restrict__ emb,
             const _Float16* __restrict__ e16, const float* __restrict__ ebias,
             float* __restrict__ out, float* __restrict__ ws) {
    __shared__ float rows_lds[128][65];     // winning e-rows, +1 pad (33 KB)
    __shared__ int idx_lds[128];
    __shared__ unsigned int hist_lds[512];

    const int tid  = threadIdx.x;
    const int lane = tid & 63;
    const int wid  = tid >> 6;
    const int pb   = blockIdx.x * 128;      // block pixel base (128-aligned)
    const int b    = pb >> 10;
    const int hw0  = pb & 1023;

    hist_lds[tid] = 0u; hist_lds[tid + 256] = 0u;

    const int col = lane & 15;   // MFMA col: pixel for A-load, code for C
    const int g   = lane >> 4;   // k-group

    // ---- issue input loads to registers FIRST (latency hides under zero-stores)
    float xv[32];
    const float* xbase = in + (size_t)b * 65536 + hw0 + wid * 32;
#pragma unroll
    for (int i = 0; i < 2; ++i) {
        const float* xp = xbase + i * 16 + col;
#pragma unroll
        for (int ks = 0; ks < 2; ++ks)
#pragma unroll
            for (int e = 0; e < 8; ++e)
                xv[i * 16 + ks * 8 + e] = xp[(size_t)(ks * 32 + g * 8 + e) * 1024];
    }

    // ---- one-hot ZERO pre-pass: 99.9% of write traffic, no data dependency.
    // Starts the HBM write stream at t=0; the winning 1.0s are scattered later.
    {
        const uint2 z = {0u, 0u};
        float* encw = out + OUT_E + (size_t)pb * 512 + tid * 2;
#pragma unroll 4
        for (int r = 0; r < 128; ++r)
            *reinterpret_cast<uint2*>(encw + (size_t)r * 512) = z;
    }

    // ---- convert staged input to A fragments (pre-scaled by -2) + |x|^2 partial
    half8 afrag[2][2];
    float sumsq = 0.0f;
#pragma unroll
    for (int i = 0; i < 2; ++i)
#pragma unroll
        for (int ks = 0; ks < 2; ++ks)
#pragma unroll
            for (int e = 0; e < 8; ++e) {
                float v = xv[i * 16 + ks * 8 + e];
                sumsq += v * v;
                afrag[i][ks][e] = (_Float16)(-2.0f * v);
            }

    // ---- 32 code-tiles of 16: acc init = |e|^2, 2 MFMA per ptile, 3-op min update
    float minv[2][4];
    int   mint[2][4];
#pragma unroll
    for (int i = 0; i < 2; ++i)
#pragma unroll
        for (int r = 0; r < 4; ++r) { minv[i][r] = __builtin_inff(); mint[i][r] = 0; }

#pragma unroll 2
    for (int t = 0; t < 32; ++t) {
        const float bias = ebias[(t << 4) + col];
        half8 bfrag[2];
#pragma unroll
        for (int ks = 0; ks < 2; ++ks)
            bfrag[ks] = *reinterpret_cast<const half8*>(
                e16 + ((size_t)((t << 4) + col) << 6) + ks * 32 + g * 8);
#pragma unroll
        for (int i = 0; i < 2; ++i) {
            f32x4 acc = { bias, bias, bias, bias };
            acc = __builtin_amdgcn_mfma_f32_16x16x32_f16(afrag[i][0], bfrag[0], acc, 0, 0, 0);
            acc = __builtin_amdgcn_mfma_f32_16x16x32_f16(afrag[i][1], bfrag[1], acc, 0, 0, 0);
#pragma unroll
            for (int r = 0; r < 4; ++r) {
                if (acc[r] < minv[i][r]) { minv[i][r] = acc[r]; mint[i][r] = t; }
            }
        }
    }

    // ---- cross-lane argmin over the 16 code-columns (pixel = g*4+r of ptile i)
    float vsum = 0.0f;   // lane-local sum of winning scores (col==0 lanes only)
#pragma unroll
    for (int i = 0; i < 2; ++i) {
#pragma unroll
        for (int r = 0; r < 4; ++r) {
            float v = minv[i][r];
            int   k = (mint[i][r] << 4) + col;
#pragma unroll
            for (int off = 1; off < 16; off <<= 1) {
                float v2 = __shfl_xor(v, off, 64);
                int   k2 = __shfl_xor(k, off, 64);
                if (v2 < v || (v2 == v && k2 < k)) { v = v2; k = k2; }
            }
            if (col == 0) {
                idx_lds[wid * 32 + i * 16 + g * 4 + r] = k;
                vsum += v;
            }
        }
    }

    // ---- per-wave loss partial: sum of (min score) + sum of |x|^2
    float lossp = vsum + sumsq;
#pragma unroll
    for (int off = 32; off > 0; off >>= 1) lossp += __shfl_down(lossp, off, 64);
    if (lane == 0) ws[512 + blockIdx.x * 4 + wid] = lossp;

    // barrier: publishes idx_lds AND drains the zero-stores (vmcnt(0) before s_barrier),
    // so the scattered 1.0 writes below cannot be overtaken by their row's zero write.
    __syncthreads();

    // ---- one-hot fixup: one 4B store per pixel into the winning slot
    if (tid < 128) {
        const int idx = idx_lds[tid];
        atomicAdd(&hist_lds[idx], 1u);      // histogram while we're here
        out[OUT_E + ((size_t)(pb + tid) << 9) + idx] = 1.0f;
    }

    // ---- stage winning e-rows: coalesced 256B row loads -> padded LDS
    for (int r = wid * 32; r < wid * 32 + 32; ++r)
        rows_lds[r][lane] = emb[((size_t)idx_lds[r] << 6) + lane];

    __syncthreads();

    // ---- quantized NCHW from LDS: conflict-free reads, pixel-coalesced stores
    {
        const int p   = tid & 127;
        const int ch0 = (tid >> 7) * 32;
        float* q = out + OUT_Q + (size_t)b * 65536 + hw0 + p;
#pragma unroll 8
        for (int c = ch0; c < ch0 + 32; ++c)
            q[(size_t)c * 1024] = rows_lds[p][c];
    }

    // ---- merge histogram into ws (skip empty bins)
    __syncthreads();
    {
        unsigned int* gh = reinterpret_cast<unsigned int*>(ws);
        unsigned int h0 = hist_lds[tid], h1 = hist_lds[tid + 256];
        if (h0) atomicAdd(&gh[tid], h0);
        if (h1) atomicAdd(&gh[tid + 256], h1);
    }
}

__global__ void vq_finalize(const float* __restrict__ ws, float* __restrict__ out) {
    __shared__ float rl[512], re[512];
    const int t = threadIdx.x;
    const unsigned int* hist = reinterpret_cast<const unsigned int*>(ws);
    const float* lp = ws + 512;
    float l = 0.0f;
#pragma unroll
    for (int j = 0; j < 8; ++j) l += lp[t + 512 * j];
    float p = (float)hist[t] * (1.0f / 131072.0f);
    rl[t] = l;
    re[t] = p * logf(p + 1e-10f);
    for (int off = 256; off > 0; off >>= 1) {
        __syncthreads();
        if (t < off) { rl[t] += rl[t + off]; re[t] += re[t + off]; }
    }
    if (t == 0) {
        out[0]     = 1.25f * rl[0] / 8388608.0f;   // (1 + commitment_cost) * mean dist
        out[OUT_P] = expf(-re[0]);                 // perplexity
    }
}

extern "C" void kernel_launch(void* const* d_in, const int* in_sizes, int n_in,
                              void* d_out, int out_size, void* d_ws, size_t ws_size,
                              hipStream_t stream) {
    (void)in_sizes; (void)n_in; (void)out_size; (void)ws_size;
    const float* in  = (const float*)d_in[0];
    const float* emb = (const float*)d_in[1];
    float* out = (float*)d_out;
    float* ws  = (float*)d_ws;
    _Float16* e16 = (_Float16*)(ws + 5120);
    float* ebias  = ws + 4608;
    unsigned int* hist = (unsigned int*)d_ws;

    vq_prep<<<dim3(64), dim3(64), 0, stream>>>(emb, e16, ebias, hist);
    vq_main<<<dim3(1024), dim3(256), 0, stream>>>(in, emb, e16, ebias, out, ws);
    vq_finalize<<<dim3(1), dim3(512), 0, stream>>>(ws, out);
}

// Round 5
// 92.656 us; speedup vs baseline: 2.1105x; 1.0768x over previous
//
#include <hip/hip_runtime.h>

typedef _Float16 half8 __attribute__((ext_vector_type(8)));
typedef _Float16 half2_t __attribute__((ext_vector_type(2)));
typedef float f32x4 __attribute__((ext_vector_type(4)));

#define OUT_Q 1ull
#define OUT_P 8388609ull
#define OUT_E 8388610ull

// ws layout (floats): [0,512) uint hist; [512,4608) per-wave loss partials;
// [4608,5120) ebias f32; [5120,...) f16 codebook (32768 halves = 64 KB)

__global__ __launch_bounds__(64)
void vq_prep(const float* __restrict__ emb, _Float16* __restrict__ e16,
             float* __restrict__ ebias, unsigned int* __restrict__ hist) {
    const int lane = threadIdx.x;       // = channel
    const int base = blockIdx.x * 8;    // 64 blocks x 8 codes
    if (lane < 8) hist[base + lane] = 0u;   // replaces a memset node
    float v[8];
#pragma unroll
    for (int j = 0; j < 8; ++j) v[j] = emb[(base + j) * 64 + lane];
#pragma unroll
    for (int j = 0; j < 8; ++j) {
        _Float16 h = (_Float16)v[j];
        e16[(base + j) * 64 + lane] = h;
        float s = (float)h * (float)h;
#pragma unroll
        for (int off = 32; off > 0; off >>= 1) s += __shfl_down(s, off, 64);
        if (lane == 0) ebias[base + j] = s;
    }
}

// All global LOADS happen before any global STORES; no mid-kernel vmcnt drains.
__global__ __launch_bounds__(512, 4)
void vq_main(const float* __restrict__ in, const _Float16* __restrict__ e16,
             const float* __restrict__ ebias, float* __restrict__ out,
             float* __restrict__ ws) {
    __shared__ __align__(16) unsigned int e16_lds[16384];  // 512 rows x 32 words, XOR-swizzled (64 KB)
    __shared__ float ebias_lds[512];
    __shared__ int idx_lds[256];
    __shared__ unsigned int hist_lds[512];

    const int tid  = threadIdx.x;
    const int lane = tid & 63;
    const int wid  = tid >> 6;              // 8 waves, 32 pixels each
    const int pb   = blockIdx.x * 256;      // block pixel base
    const int b    = pb >> 10;
    const int hw0  = pb & 1023;
    const int col  = lane & 15;             // MFMA col: pixel for A, code for C
    const int g    = lane >> 4;             // k-group

    // ---- input loads first (HBM latency hides under LDS staging)
    float xv[32];
    const float* xbase = in + (size_t)b * 65536 + hw0 + wid * 32;
#pragma unroll
    for (int i = 0; i < 2; ++i) {
        const float* xp = xbase + i * 16 + col;
#pragma unroll
        for (int ks = 0; ks < 2; ++ks)
#pragma unroll
            for (int e = 0; e < 8; ++e)
                xv[i * 16 + ks * 8 + e] = xp[(size_t)(ks * 32 + g * 8 + e) * 1024];
    }

    // ---- stage f16 codebook -> LDS, word-XOR swizzle: word' = word ^ ((row&7)<<2)
    // (keeps 16B contiguity; spreads column-reads across 8 bank groups)
    {
        const uint4* gsrc = reinterpret_cast<const uint4*>(e16);  // 4096 x 16B
#pragma unroll
        for (int it = 0; it < 8; ++it) {
            const int u4i = it * 512 + tid;
            uint4 v = gsrc[u4i];
            const int r  = u4i >> 3;          // 8 uint4 per row
            const int wb = (u4i & 7) * 4;     // word base (4-aligned)
            *reinterpret_cast<uint4*>(&e16_lds[r * 32 + (wb ^ ((r & 7) << 2))]) = v;
        }
        ebias_lds[tid] = ebias[tid];
        hist_lds[tid] = 0u;
    }

    // ---- A fragments (pre-scaled by -2) + |x|^2 partial
    half8 afrag[2][2];
    float sumsq = 0.0f;
#pragma unroll
    for (int i = 0; i < 2; ++i)
#pragma unroll
        for (int ks = 0; ks < 2; ++ks)
#pragma unroll
            for (int e = 0; e < 8; ++e) {
                float v = xv[i * 16 + ks * 8 + e];
                sumsq += v * v;
                afrag[i][ks][e] = (_Float16)(-2.0f * v);
            }

    __syncthreads();   // staging visible (outstanding vmem: none unconsumed)

    // ---- 32 code-tiles: acc init = |e|^2, B-frags from swizzled LDS
    float minv[2][4];
    int   mint[2][4];
#pragma unroll
    for (int i = 0; i < 2; ++i)
#pragma unroll
        for (int r = 0; r < 4; ++r) { minv[i][r] = __builtin_inff(); mint[i][r] = 0; }

    const int bswz = (col & 7) << 2;   // row&7 == col&7 for row = t*16+col
#pragma unroll 2
    for (int t = 0; t < 32; ++t) {
        const float bias = ebias_lds[(t << 4) + col];
        half8 bfrag[2];
#pragma unroll
        for (int ks = 0; ks < 2; ++ks)
            bfrag[ks] = *reinterpret_cast<const half8*>(
                &e16_lds[t * 512 + col * 32 + ((ks * 16 + g * 4) ^ bswz)]);
#pragma unroll
        for (int i = 0; i < 2; ++i) {
            f32x4 acc = { bias, bias, bias, bias };
            acc = __builtin_amdgcn_mfma_f32_16x16x32_f16(afrag[i][0], bfrag[0], acc, 0, 0, 0);
            acc = __builtin_amdgcn_mfma_f32_16x16x32_f16(afrag[i][1], bfrag[1], acc, 0, 0, 0);
#pragma unroll
            for (int r = 0; r < 4; ++r) {
                if (acc[r] < minv[i][r]) { minv[i][r] = acc[r]; mint[i][r] = t; }
            }
        }
    }

    // ---- cross-lane argmin over the 16 code-columns (pixel = g*4+r of ptile i)
    float vsum = 0.0f;
#pragma unroll
    for (int i = 0; i < 2; ++i) {
#pragma unroll
        for (int r = 0; r < 4; ++r) {
            float v = minv[i][r];
            int   k = (mint[i][r] << 4) + col;
#pragma unroll
            for (int off = 1; off < 16; off <<= 1) {
                float v2 = __shfl_xor(v, off, 64);
                int   k2 = __shfl_xor(k, off, 64);
                if (v2 < v || (v2 == v && k2 < k)) { v = v2; k = k2; }
            }
            if (col == 0) {
                idx_lds[wid * 32 + i * 16 + g * 4 + r] = k;
                vsum += v;
            }
        }
    }

    // per-wave loss partial (stored later, after the last barrier)
    float lossp = vsum + sumsq;
#pragma unroll
    for (int off = 32; off > 0; off >>= 1) lossp += __shfl_down(lossp, off, 64);

    __syncthreads();   // idx_lds visible (vmcnt already 0 -> cheap)

    if (tid < 256) atomicAdd(&hist_lds[idx_lds[tid]], 1u);

    __syncthreads();   // hist complete (lgkm only -> cheap)

    // ================= store-only phase: no loads below, no barriers below ====

    if (lane == 0) ws[512 + blockIdx.x * 8 + wid] = lossp;
    {
        unsigned int h = hist_lds[tid];
        if (h) atomicAdd(&reinterpret_cast<unsigned int*>(ws)[tid], h);
    }

    // ---- quantized NCHW from LDS f16 rows (exact cvt), pixel-coalesced stores
    {
        const int p   = tid & 255;
        const int ch0 = (tid >> 8) * 32;
        const int R   = idx_lds[p];
        const int qswz = (R & 7) << 2;
        float* q = out + OUT_Q + (size_t)b * 65536 + hw0 + p;
#pragma unroll
        for (int j = 0; j < 4; ++j) {
            uint4 u = *reinterpret_cast<const uint4*>(
                &e16_lds[R * 32 + (((ch0 >> 1) + j * 4) ^ qswz)]);
            const int c = ch0 + j * 8;
            half2_t h0 = __builtin_bit_cast(half2_t, u.x);
            half2_t h1 = __builtin_bit_cast(half2_t, u.y);
            half2_t h2 = __builtin_bit_cast(half2_t, u.z);
            half2_t h3 = __builtin_bit_cast(half2_t, u.w);
            q[(size_t)(c + 0) * 1024] = (float)h0.x;
            q[(size_t)(c + 1) * 1024] = (float)h0.y;
            q[(size_t)(c + 2) * 1024] = (float)h1.x;
            q[(size_t)(c + 3) * 1024] = (float)h1.y;
            q[(size_t)(c + 4) * 1024] = (float)h2.x;
            q[(size_t)(c + 5) * 1024] = (float)h2.y;
            q[(size_t)(c + 6) * 1024] = (float)h3.x;
            q[(size_t)(c + 7) * 1024] = (float)h3.y;
        }
    }

    // ---- one-hot rows written once, 1.0 in place; 512 thr x 8B = two 2KB rows/instr
    {
        const int cp = (tid & 255) * 2;       // column pair
        const int rh = (tid >> 8) * 128;      // row half
        float* encw = out + OUT_E + ((size_t)(pb + rh)) * 512 + cp;
#pragma unroll 2
        for (int rr = 0; rr < 128; rr += 2) {
            const int i0 = idx_lds[rh + rr];
            const int i1 = idx_lds[rh + rr + 1];
            uint2 v0, v1;
            v0.x = (cp     == i0) ? 0x3f800000u : 0u;
            v0.y = (cp + 1 == i0) ? 0x3f800000u : 0u;
            v1.x = (cp     == i1) ? 0x3f800000u : 0u;
            v1.y = (cp + 1 == i1) ? 0x3f800000u : 0u;
            *reinterpret_cast<uint2*>(encw + (size_t)rr * 512)       = v0;
            *reinterpret_cast<uint2*>(encw + (size_t)(rr + 1) * 512) = v1;
        }
    }
}

__global__ void vq_finalize(const float* __restrict__ ws, float* __restrict__ out) {
    __shared__ float rl[512], re[512];
    const int t = threadIdx.x;
    const unsigned int* hist = reinterpret_cast<const unsigned int*>(ws);
    const float* lp = ws + 512;
    float l = 0.0f;
#pragma unroll
    for (int j = 0; j < 8; ++j) l += lp[t + 512 * j];
    float p = (float)hist[t] * (1.0f / 131072.0f);
    rl[t] = l;
    re[t] = p * logf(p + 1e-10f);
    for (int off = 256; off > 0; off >>= 1) {
        __syncthreads();
        if (t < off) { rl[t] += rl[t + off]; re[t] += re[t + off]; }
    }
    if (t == 0) {
        out[0]     = 1.25f * rl[0] / 8388608.0f;   // (1 + commitment_cost) * mean dist
        out[OUT_P] = expf(-re[0]);                 // perplexity
    }
}

extern "C" void kernel_launch(void* const* d_in, const int* in_sizes, int n_in,
                              void* d_out, int out_size, void* d_ws, size_t ws_size,
                              hipStream_t stream) {
    (void)in_sizes; (void)n_in; (void)out_size; (void)ws_size;
    const float* in  = (const float*)d_in[0];
    const float* emb = (const float*)d_in[1];
    float* out = (float*)d_out;
    float* ws  = (float*)d_ws;
    _Float16* e16 = (_Float16*)(ws + 5120);
    float* ebias  = ws + 4608;
    unsigned int* hist = (unsigned int*)d_ws;

    vq_prep<<<dim3(64), dim3(64), 0, stream>>>(emb, e16, ebias, hist);
    vq_main<<<dim3(512), dim3(512), 0, stream>>>(in, e16, ebias, out, ws);
    vq_finalize<<<dim3(1), dim3(512), 0, stream>>>(ws, out);
}